// Round 1
// baseline (3810.872 us; speedup 1.0000x reference)
//
#include <hip/hip_runtime.h>

// NonLocalMeans: rgb (8,3,1024,1024) f32, search 11x11, patch 5x5, circular.
// out(p) = sum_s w(p,s)*rgb(p-s) / sum_s w(p,s),
// w(p,s) = exp(-sqrt(sum_{5x5 patch} (y - y_shifted)^2) * inv_h)

#define HW (1024 * 1024)
#define W 1024
#define MASK 1023

constexpr int TILE = 32;
constexpr int YREG = 46;    // TILE + 2*7 (shift 5 + patch 2)
constexpr int YPITCH = 48;
constexpr int CREG = 42;    // TILE + 2*5
// -log2(e) / (1.0 + 1e-6)
constexpr float NEG_C = -1.4426935981939074f;

__global__ void nlm_fused(const float* __restrict__ rgb, float* __restrict__ out) {
    __shared__ float  ldsY[YREG * YPITCH];      // 8832 B
    __shared__ float4 ldsC[CREG * CREG];        // 28224 B

    const int tid = threadIdx.x;
    const int batch = blockIdx.z;
    const int by0 = blockIdx.y * TILE;
    const int bx0 = blockIdx.x * TILE;

    const float* base = rgb + (size_t)batch * 3 * HW;

    // ---- stage luminance tile (mean over channels), halo 7 ----
    for (int i = tid; i < YREG * YREG; i += 256) {
        int ry = i / YREG, rx = i - ry * YREG;
        int gy = (by0 + ry - 7) & MASK;
        int gx = (bx0 + rx - 7) & MASK;
        int off = gy * W + gx;
        float v = (base[off] + base[off + HW] + base[off + 2 * HW]) * (1.0f / 3.0f);
        ldsY[ry * YPITCH + rx] = v;
    }
    // ---- stage rgb tile as float4, halo 5 ----
    for (int i = tid; i < CREG * CREG; i += 256) {
        int ry = i / CREG, rx = i - ry * CREG;
        int gy = (by0 + ry - 5) & MASK;
        int gx = (bx0 + rx - 5) & MASK;
        int off = gy * W + gx;
        ldsC[i] = make_float4(base[off], base[off + HW], base[off + 2 * HW], 0.0f);
    }
    __syncthreads();

    const int tx = tid & 31;          // output column within tile
    const int y0 = (tid >> 5) * 4;    // 4-pixel column run per thread

    float accR[4] = {0.f, 0.f, 0.f, 0.f};
    float accG[4] = {0.f, 0.f, 0.f, 0.f};
    float accB[4] = {0.f, 0.f, 0.f, 0.f};
    float accW[4] = {0.f, 0.f, 0.f, 0.f};

    for (int dy = -5; dy <= 5; ++dy) {
        float h[5][11];   // ring of horizontal 5-sums, rows rr-4..rr
        #pragma unroll
        for (int rr = 0; rr < 8; ++rr) {
            const int r  = y0 - 2 + rr;   // tile-local row, [-2, 33]
            const int rs = r - dy;        // shifted row, [-7, 38]
            const float* ycp = &ldsY[(r + 7) * YPITCH + tx + 5];
            const float* ywp = &ldsY[(rs + 7) * YPITCH + tx];
            const float c0 = ycp[0], c1 = ycp[1], c2 = ycp[2], c3 = ycp[3], c4 = ycp[4];
            float wv[15];
            #pragma unroll
            for (int j = 0; j < 15; ++j) wv[j] = ywp[j];
            // horizontal 5-sums for all 11 dx via sliding window
            #pragma unroll
            for (int dxi = 0; dxi < 11; ++dxi) {
                // window index j = b + 10 - dxi  (dx = dxi - 5)
                float d0 = c0 - wv[10 - dxi];
                float d1 = c1 - wv[11 - dxi];
                float d2 = c2 - wv[12 - dxi];
                float d3 = c3 - wv[13 - dxi];
                float d4 = c4 - wv[14 - dxi];
                float s = d0 * d0;
                s = fmaf(d1, d1, s);
                s = fmaf(d2, d2, s);
                s = fmaf(d3, d3, s);
                s = fmaf(d4, d4, s);
                h[rr % 5][dxi] = s;
            }
            if (rr >= 4) {
                const int yo = rr - 4;    // output row 0..3
                const float4* crow = &ldsC[(y0 + yo - dy + 5) * CREG + tx + 10];
                #pragma unroll
                for (int dxi = 0; dxi < 11; ++dxi) {
                    // all 5 ring slots hold rows yo-2..yo+2 for this dy
                    float v = h[0][dxi] + h[1][dxi] + h[2][dxi] + h[3][dxi] + h[4][dxi];
                    float dist = __builtin_amdgcn_sqrtf(v);
                    float w = __builtin_amdgcn_exp2f(dist * NEG_C);
                    float4 px = crow[-dxi];
                    accR[yo] = fmaf(w, px.x, accR[yo]);
                    accG[yo] = fmaf(w, px.y, accG[yo]);
                    accB[yo] = fmaf(w, px.z, accB[yo]);
                    accW[yo] += w;
                }
            }
        }
    }

    float* obase = out + (size_t)batch * 3 * HW;
    #pragma unroll
    for (int yo = 0; yo < 4; ++yo) {
        const int gy = by0 + y0 + yo;
        const int gx = bx0 + tx;
        const int off = gy * W + gx;
        const float inv = 1.0f / accW[yo];
        obase[off]          = accR[yo] * inv;
        obase[off + HW]     = accG[yo] * inv;
        obase[off + 2 * HW] = accB[yo] * inv;
    }
}

extern "C" void kernel_launch(void* const* d_in, const int* in_sizes, int n_in,
                              void* d_out, int out_size, void* d_ws, size_t ws_size,
                              hipStream_t stream) {
    const float* rgb = (const float*)d_in[0];
    float* out = (float*)d_out;
    dim3 grid(W / TILE, W / TILE, 8);
    dim3 block(256, 1, 1);
    hipLaunchKernelGGL(nlm_fused, grid, block, 0, stream, rgb, out);
}